// Round 1
// baseline (3276.680 us; speedup 1.0000x reference)
//
#include <hip/hip_runtime.h>

// ---------------------------------------------------------------------------
// Fused MANN: gating (GEMV64 + LN + relu + GEMV4 + softmax) ->
//             expert L1 (256->128, K=4 blended, LN, relu) ->
//             expert L2 (128->128, K=4 blended, LN, relu) ->
//             expert L3 (128->3,  K=4 blended)
// One block = 64 rows. 256 threads = 16 row-groups x 16 out-groups.
// Per thread: 4 rows x 8 outs (128-wide layers). Blend folded into x operand.
// All weights stream from global (L2-resident, ~850KB total). Activations in LDS.
// ---------------------------------------------------------------------------

constexpr int B_TOT = 131072;
constexpr int IN    = 256;
constexpr int HID   = 128;
constexpr int GH    = 64;
constexpr int KEXP  = 4;
constexpr int NA    = 3;
constexpr int ROWS  = 64;        // rows per block
constexpr int XS    = IN + 4;    // padded stride for x tile (floats)
constexpr int YS    = HID + 4;   // padded stride for hidden tiles
constexpr int HS    = GH + 4;    // padded stride for gating hidden
constexpr float EPS = 1e-5f;

// Generic blended expert layer: sout[r][o] = relu(LN_o( sum_k bl[r][k] *
//   (dot(sin[r], W[k][o]) + eb[k][o]) ))
template<int L, int SIN>
__device__ __forceinline__ void expert_layer(
    const float* sin_, float* sout,
    const float bl[4][4], int r0, int og,
    const float* __restrict__ W, const float* __restrict__ eb,
    const float* __restrict__ lg, const float* __restrict__ lb)
{
  float acc[4][8];
#pragma unroll
  for (int r = 0; r < 4; ++r)
#pragma unroll
    for (int j = 0; j < 8; ++j) acc[r][j] = 0.f;

  for (int ic = 0; ic < L / 4; ++ic) {
    float4 xv[4];
#pragma unroll
    for (int r = 0; r < 4; ++r)
      xv[r] = *(const float4*)&sin_[(r0 + r) * SIN + ic * 4];
#pragma unroll
    for (int k = 0; k < KEXP; ++k) {
      float4 tx[4];
#pragma unroll
      for (int r = 0; r < 4; ++r) {
        const float s = bl[r][k];
        tx[r].x = s * xv[r].x; tx[r].y = s * xv[r].y;
        tx[r].z = s * xv[r].z; tx[r].w = s * xv[r].w;
      }
#pragma unroll
      for (int j = 0; j < 8; ++j) {
        const float4 wv =
            *(const float4*)&W[((size_t)(k * HID + og * 8 + j)) * L + ic * 4];
#pragma unroll
        for (int r = 0; r < 4; ++r)
          acc[r][j] = fmaf(tx[r].x, wv.x,
                      fmaf(tx[r].y, wv.y,
                      fmaf(tx[r].z, wv.z,
                      fmaf(tx[r].w, wv.w, acc[r][j]))));
      }
    }
  }

  // blended bias
#pragma unroll
  for (int j = 0; j < 8; ++j) {
    const int o = og * 8 + j;
#pragma unroll
    for (int k = 0; k < KEXP; ++k) {
      const float ebv = eb[k * HID + o];
#pragma unroll
      for (int r = 0; r < 4; ++r) acc[r][j] += bl[r][k] * ebv;
    }
  }

  // LayerNorm over 128 outs (8 per thread x 16 og-lanes) + relu + store
#pragma unroll
  for (int r = 0; r < 4; ++r) {
    float s = 0.f;
#pragma unroll
    for (int j = 0; j < 8; ++j) s += acc[r][j];
#pragma unroll
    for (int m = 1; m < 16; m <<= 1) s += __shfl_xor(s, m, 64);
    const float mu = s * (1.0f / 128.0f);
    float q = 0.f;
#pragma unroll
    for (int j = 0; j < 8; ++j) { const float d = acc[r][j] - mu; q += d * d; }
#pragma unroll
    for (int m = 1; m < 16; m <<= 1) q += __shfl_xor(q, m, 64);
    const float rstd = rsqrtf(q * (1.0f / 128.0f) + EPS);
#pragma unroll
    for (int j = 0; j < 8; ++j) {
      const int o = og * 8 + j;
      const float y = (acc[r][j] - mu) * rstd * lg[o] + lb[o];
      sout[(r0 + r) * YS + o] = fmaxf(y, 0.f);
    }
  }
}

__global__ __launch_bounds__(256, 1) void mann_fused(
    const float* __restrict__ state,
    const float* __restrict__ gw1, const float* __restrict__ gb1,
    const float* __restrict__ gln_g, const float* __restrict__ gln_b,
    const float* __restrict__ gw2, const float* __restrict__ gb2,
    const float* __restrict__ temperature,
    const float* __restrict__ e1_w, const float* __restrict__ e1_b,
    const float* __restrict__ ln1_g, const float* __restrict__ ln1_b,
    const float* __restrict__ e2_w, const float* __restrict__ e2_b,
    const float* __restrict__ ln2_g, const float* __restrict__ ln2_b,
    const float* __restrict__ e3_w, const float* __restrict__ e3_b,
    float* __restrict__ out_policy, float* __restrict__ out_blend)
{
  // LDS: x tile (64x260) | a tile (64x132, doubles as gating-h 64x68) | blend
  // b tile overlays the x tile (x is dead after layer 1).
  __shared__ float smem[ROWS * XS + ROWS * YS + ROWS * KEXP];
  float* sx  = smem;
  float* sa  = smem + ROWS * XS;
  float* sb  = smem;                       // overlay: valid after layer-1 sync
  float* sh  = sa;                         // gating hidden, stride HS
  float* sbl = smem + ROWS * XS + ROWS * YS;

  const int tid = threadIdx.x;
  const int rowbase = blockIdx.x * ROWS;
  const int rowg = tid >> 4, og = tid & 15;
  const int r0 = rowg * 4;

  // ---- Phase A: stage 64x256 fp32 x-tile (fully coalesced float4) ----
  {
    const float4* gsrc =
        reinterpret_cast<const float4*>(state + (size_t)rowbase * IN);
#pragma unroll
    for (int it = 0; it < 16; ++it) {
      const int fi = tid + it * 256;        // 0..4095
      const int row = fi >> 6, c4 = fi & 63;
      const float4 v = gsrc[fi];
      *reinterpret_cast<float4*>(&sx[row * XS + c4 * 4]) = v;
    }
  }
  __syncthreads();

  // ---- Phase B: gating ----
  {
    float acc[4][4];
#pragma unroll
    for (int r = 0; r < 4; ++r)
#pragma unroll
      for (int j = 0; j < 4; ++j) acc[r][j] = 0.f;

    for (int ic = 0; ic < IN / 4; ++ic) {
      float4 xv[4];
#pragma unroll
      for (int r = 0; r < 4; ++r)
        xv[r] = *(const float4*)&sx[(r0 + r) * XS + ic * 4];
#pragma unroll
      for (int j = 0; j < 4; ++j) {
        const float4 wv = *(const float4*)&gw1[(og * 4 + j) * IN + ic * 4];
#pragma unroll
        for (int r = 0; r < 4; ++r)
          acc[r][j] = fmaf(xv[r].x, wv.x,
                      fmaf(xv[r].y, wv.y,
                      fmaf(xv[r].z, wv.z,
                      fmaf(xv[r].w, wv.w, acc[r][j]))));
      }
    }

    // +bias, LN over 64, relu, store h
#pragma unroll
    for (int r = 0; r < 4; ++r) {
      float v[4];
      float s = 0.f;
#pragma unroll
      for (int j = 0; j < 4; ++j) {
        v[j] = acc[r][j] + gb1[og * 4 + j];
        s += v[j];
      }
#pragma unroll
      for (int m = 1; m < 16; m <<= 1) s += __shfl_xor(s, m, 64);
      const float mu = s * (1.0f / 64.0f);
      float q = 0.f;
#pragma unroll
      for (int j = 0; j < 4; ++j) { const float d = v[j] - mu; q += d * d; }
#pragma unroll
      for (int m = 1; m < 16; m <<= 1) q += __shfl_xor(q, m, 64);
      const float rstd = rsqrtf(q * (1.0f / 64.0f) + EPS);
#pragma unroll
      for (int j = 0; j < 4; ++j) {
        const int o = og * 4 + j;
        const float hh = (v[j] - mu) * rstd * gln_g[o] + gln_b[o];
        sh[(r0 + r) * HS + o] = fmaxf(hh, 0.f);
      }
    }
  }
  __syncthreads();

  // ---- Phase B2: logits + softmax -> blend ----
  {
    const int row = tid >> 2, k = tid & 3;
    float s = 0.f;
    for (int i = 0; i < GH; ++i) s += sh[row * HS + i] * gw2[k * GH + i];
    s += gb2[k];
    float t = temperature[0];
    t = fminf(fmaxf(t, 0.1f), 2.0f);
    s = s / t;
    float m = s;
    m = fmaxf(m, __shfl_xor(m, 1, 64));
    m = fmaxf(m, __shfl_xor(m, 2, 64));
    const float e = expf(s - m);
    float sum = e;
    sum += __shfl_xor(sum, 1, 64);
    sum += __shfl_xor(sum, 2, 64);
    const float bl = e / sum;
    sbl[row * 4 + k] = bl;
    out_blend[(size_t)(rowbase + row) * 4 + k] = bl;
  }
  __syncthreads();

  // blends for my 4 rows into registers
  float bl[4][4];
#pragma unroll
  for (int r = 0; r < 4; ++r)
#pragma unroll
    for (int k = 0; k < 4; ++k) bl[r][k] = sbl[(r0 + r) * 4 + k];

  // ---- Phase C: expert layer 1 (256 -> 128), writes sa ----
  expert_layer<IN, XS>(sx, sa, bl, r0, og, e1_w, e1_b, ln1_g, ln1_b);
  __syncthreads();

  // ---- Phase D: expert layer 2 (128 -> 128), writes sb (overlays sx) ----
  expert_layer<HID, YS>(sa, sb, bl, r0, og, e2_w, e2_b, ln2_g, ln2_b);
  __syncthreads();

  // ---- Phase E: expert layer 3 (128 -> 3) + blend reduce ----
  {
    const int row = tid >> 2, k = tid & 3;
    float p[NA] = {0.f, 0.f, 0.f};
    for (int ic = 0; ic < HID / 4; ++ic) {
      const float4 xv = *(const float4*)&sb[row * YS + ic * 4];
#pragma unroll
      for (int a = 0; a < NA; ++a) {
        const float4 wv =
            *(const float4*)&e3_w[((size_t)(k * NA + a)) * HID + ic * 4];
        p[a] = fmaf(xv.x, wv.x,
               fmaf(xv.y, wv.y,
               fmaf(xv.z, wv.z,
               fmaf(xv.w, wv.w, p[a]))));
      }
    }
    const float blk = sbl[row * 4 + k];
#pragma unroll
    for (int a = 0; a < NA; ++a) p[a] = blk * (p[a] + e3_b[k * NA + a]);
#pragma unroll
    for (int a = 0; a < NA; ++a) {
      p[a] += __shfl_xor(p[a], 1, 64);
      p[a] += __shfl_xor(p[a], 2, 64);
    }
    if (k == 0) {
      const size_t o = (size_t)(rowbase + row) * NA;
      out_policy[o + 0] = p[0];
      out_policy[o + 1] = p[1];
      out_policy[o + 2] = p[2];
    }
  }
}

extern "C" void kernel_launch(void* const* d_in, const int* in_sizes, int n_in,
                              void* d_out, int out_size, void* d_ws, size_t ws_size,
                              hipStream_t stream) {
  const float* state = (const float*)d_in[0];
  const float* gw1   = (const float*)d_in[1];
  const float* gb1   = (const float*)d_in[2];
  const float* gln_g = (const float*)d_in[3];
  const float* gln_b = (const float*)d_in[4];
  const float* gw2   = (const float*)d_in[5];
  const float* gb2   = (const float*)d_in[6];
  const float* temp  = (const float*)d_in[7];
  const float* e1_w  = (const float*)d_in[8];
  const float* e1_b  = (const float*)d_in[9];
  const float* ln1_g = (const float*)d_in[10];
  const float* ln1_b = (const float*)d_in[11];
  const float* e2_w  = (const float*)d_in[12];
  const float* e2_b  = (const float*)d_in[13];
  const float* ln2_g = (const float*)d_in[14];
  const float* ln2_b = (const float*)d_in[15];
  const float* e3_w  = (const float*)d_in[16];
  const float* e3_b  = (const float*)d_in[17];

  float* out_policy = (float*)d_out;                       // [B,3]
  float* out_blend  = (float*)d_out + (size_t)B_TOT * NA;  // [B,4]

  const int grid = B_TOT / ROWS;  // 2048
  mann_fused<<<grid, 256, 0, stream>>>(
      state, gw1, gb1, gln_g, gln_b, gw2, gb2, temp,
      e1_w, e1_b, ln1_g, ln1_b, e2_w, e2_b, ln2_g, ln2_b, e3_w, e3_b,
      out_policy, out_blend);
}